// Round 1
// baseline (1321.222 us; speedup 1.0000x reference)
//
#include <hip/hip_runtime.h>
#include <hip/hip_bf16.h>

#define D_DIM 512
#define S_LEN 12
#define H_NUM 8
#define HD 64
#define G_B 8
#define ROWS 96           // G_B * S_LEN
#define THREADS 512
#define XS 520            // X LDS stride in bf16 elems (pad 8: 1040B rows, 16B-aligned, 2-way banks)
#define QS 72             // Q/K/V/attn LDS stride (144B rows, 16B-aligned, 2-way banks)
#define WMAT 262144       // 512*512

// smem byte offsets
#define X_OFF   0
#define Q_OFF   99840
#define K_OFF   113664
#define V_OFF   127488
#define A_OFF   141312
#define P_OFF   155136            // union: Pl [8][12][16] f32  OR  red [96][8][2] f32
#define MU_OFF  (155136 + 6144)   // musig [96][2] f32
#define SMEM_BYTES 162048

typedef __attribute__((ext_vector_type(8))) short bf16x8;
typedef __attribute__((ext_vector_type(4))) float f32x4;

__device__ __forceinline__ unsigned short f2bf(float f) {
    union { float f; unsigned u; } c; c.f = f;
    unsigned r = c.u + 0x7fffu + ((c.u >> 16) & 1u);
    return (unsigned short)(r >> 16);
}
__device__ __forceinline__ float bf2f(unsigned short u) {
    union { unsigned u; float f; } c; c.u = ((unsigned)u) << 16;
    return c.f;
}

__global__ void prep_weights(const float* __restrict__ Wq, const float* __restrict__ Wk,
                             const float* __restrict__ Wv, const float* __restrict__ Wo,
                             unsigned short* __restrict__ wt) {
    int idx = blockIdx.x * 256 + threadIdx.x;   // 0 .. 4*WMAT-1
    int mat = idx >> 18;
    int rem = idx & (WMAT - 1);
    int e = rem >> 9, d = rem & 511;
    const float* W = (mat == 0) ? Wq : (mat == 1) ? Wk : (mat == 2) ? Wv : Wo;
    wt[idx] = f2bf(W[d * D_DIM + e]);           // wt[mat][e][d] = W[d][e]
}

__global__ __launch_bounds__(THREADS, 2) void fused_attn(
    const float* __restrict__ x, const unsigned short* __restrict__ wt,
    const float* __restrict__ bq, const float* __restrict__ bk, const float* __restrict__ bv,
    const float* __restrict__ adj, const float* __restrict__ bo,
    const float* __restrict__ gamma, const float* __restrict__ beta,
    float* __restrict__ out)
{
    extern __shared__ char smem[];
    unsigned short* Xl = (unsigned short*)(smem + X_OFF);   // [96][520] bf16
    unsigned short* Ql = (unsigned short*)(smem + Q_OFF);   // [96][72]  bf16
    unsigned short* Kl = (unsigned short*)(smem + K_OFF);
    unsigned short* Vl = (unsigned short*)(smem + V_OFF);
    unsigned short* Al = (unsigned short*)(smem + A_OFF);   // attn out [96][72] bf16
    float* Pl    = (float*)(smem + P_OFF);                  // [8 waves][12][16]
    float* red   = (float*)(smem + P_OFF);                  // [96][8][2] (time-disjoint union with Pl)
    float* musig = (float*)(smem + MU_OFF);                 // [96][2]

    const int tid  = threadIdx.x;
    const int lane = tid & 63;
    const int w    = tid >> 6;          // wave 0..7
    const int lr   = lane & 15;         // fragment row/col lane index
    const int lg   = lane >> 4;         // fragment k-group
    const int wrow = w >> 2, wcol = w & 3;
    const size_t row0 = (size_t)blockIdx.x * ROWS;

    // ---------------- phase 0: stage X -> LDS (bf16) ----------------
    #pragma unroll
    for (int it = 0; it < 24; ++it) {
        int idx = it * THREADS + tid;            // 0..12287 chunks of 4 floats
        int r = idx >> 7, c = (idx & 127) << 2;
        float4 v = *(const float4*)(x + (row0 + r) * (size_t)D_DIM + c);
        ushort4 pk;
        pk.x = f2bf(v.x); pk.y = f2bf(v.y); pk.z = f2bf(v.z); pk.w = f2bf(v.w);
        *(ushort4*)(Xl + r * XS + c) = pk;
    }
    __syncthreads();

    // persistent output accumulators: wave owns all 96 rows x cols [w*64, w*64+64)
    f32x4 Y[6][4];
    #pragma unroll
    for (int mt = 0; mt < 6; ++mt)
        #pragma unroll
        for (int nt = 0; nt < 4; ++nt) Y[mt][nt] = (f32x4){0.f, 0.f, 0.f, 0.f};

    const float* bptr[3] = {bq, bk, bv};

    for (int h = 0; h < H_NUM; ++h) {
        // ---------------- QKV projection for head h ----------------
        // wave (wrow,wcol): M-tiles wrow*3..+2 (rows wrow*48..+47), col-tile wcol (cols wcol*16..+15 of head) x 3 matrices
        f32x4 acc[3][3];
        #pragma unroll
        for (int a = 0; a < 3; ++a)
            #pragma unroll
            for (int b2 = 0; b2 < 3; ++b2) acc[a][b2] = (f32x4){0.f, 0.f, 0.f, 0.f};

        #pragma unroll
        for (int ks = 0; ks < 16; ++ks) {
            bf16x8 af[3];
            #pragma unroll
            for (int mt = 0; mt < 3; ++mt)
                af[mt] = *(const bf16x8*)(Xl + (wrow * 48 + mt * 16 + lr) * XS + ks * 32 + lg * 8);
            #pragma unroll
            for (int mat = 0; mat < 3; ++mat) {
                bf16x8 bf = *(const bf16x8*)(wt + mat * WMAT +
                                             (h * HD + wcol * 16 + lr) * D_DIM + ks * 32 + lg * 8);
                #pragma unroll
                for (int mt = 0; mt < 3; ++mt)
                    acc[mat][mt] = __builtin_amdgcn_mfma_f32_16x16x32_bf16(af[mt], bf, acc[mat][mt], 0, 0, 0);
            }
        }
        {
            int colh = wcol * 16 + lr;   // 0..63 within head
            #pragma unroll
            for (int mat = 0; mat < 3; ++mat) {
                float bias = bptr[mat][h * HD + colh];
                unsigned short* T = (mat == 0) ? Ql : (mat == 1) ? Kl : Vl;
                #pragma unroll
                for (int mt = 0; mt < 3; ++mt)
                    #pragma unroll
                    for (int j = 0; j < 4; ++j) {
                        int rowl = wrow * 48 + mt * 16 + lg * 4 + j;   // D-layout: row=(lg*4+j), col=lr
                        T[rowl * QS + colh] = f2bf(acc[mat][mt][j] + bias);
                    }
            }
        }
        __syncthreads();

        // ---------------- attention: wave w handles batch item bb=w ----------------
        const int rb = w * S_LEN;
        f32x4 sacc = (f32x4){0.f, 0.f, 0.f, 0.f};
        #pragma unroll
        for (int ks = 0; ks < 2; ++ks) {
            // swapped: D[t][s] = sum_d K[t][d]*Q[s][d]  (A=K rows t=lr, B=Q cols s=lr)
            bf16x8 ak = *(const bf16x8*)(Kl + (rb + lr) * QS + ks * 32 + lg * 8);
            bf16x8 aq = *(const bf16x8*)(Ql + (rb + lr) * QS + ks * 32 + lg * 8);
            sacc = __builtin_amdgcn_mfma_f32_16x16x32_bf16(ak, aq, sacc, 0, 0, 0);
        }
        const int s_idx = lr;                       // this lane's q-row (col of D)
        float sc[4], e4[4];
        float m = -1e30f;
        #pragma unroll
        for (int j = 0; j < 4; ++j) {
            int t = lg * 4 + j;                     // k-row (row of D)
            float ab = (s_idx < 12 && t < 12) ? adj[(h * S_LEN + s_idx) * S_LEN + t] : 0.f;
            sc[j] = (t < 12) ? (sacc[j] * 0.125f + ab) : -1e30f;
            m = fmaxf(m, sc[j]);
        }
        m = fmaxf(m, __shfl_xor(m, 16));
        m = fmaxf(m, __shfl_xor(m, 32));
        float ssum = 0.f;
        #pragma unroll
        for (int j = 0; j < 4; ++j) { e4[j] = __expf(sc[j] - m); ssum += e4[j]; }
        ssum += __shfl_xor(ssum, 16);
        ssum += __shfl_xor(ssum, 32);
        float inv = 1.f / ssum;
        if (s_idx < 12) {
            float* Pw = Pl + w * 192;
            #pragma unroll
            for (int j = 0; j < 4; ++j) Pw[s_idx * 16 + lg * 4 + j] = e4[j] * inv;
        }
        __syncthreads();

        // PV: lane = dim d (0..63); P broadcast from LDS
        {
            float vv[12];
            #pragma unroll
            for (int t = 0; t < 12; ++t) vv[t] = bf2f(Vl[(rb + t) * QS + lane]);
            const float* Pw = Pl + w * 192;
            #pragma unroll
            for (int ss = 0; ss < 12; ++ss) {
                f32x4 pa = *(const f32x4*)(Pw + ss * 16);
                f32x4 pb = *(const f32x4*)(Pw + ss * 16 + 4);
                f32x4 pc = *(const f32x4*)(Pw + ss * 16 + 8);
                float o = 0.f;
                #pragma unroll
                for (int t = 0; t < 4; ++t) o += pa[t] * vv[t];
                #pragma unroll
                for (int t = 0; t < 4; ++t) o += pb[t] * vv[4 + t];
                #pragma unroll
                for (int t = 0; t < 4; ++t) o += pc[t] * vv[8 + t];
                Al[(rb + ss) * QS + lane] = f2bf(o);
            }
        }
        __syncthreads();

        // ---------------- out-projection accumulate (K-slice = this head) ----------------
        #pragma unroll
        for (int ks = 0; ks < 2; ++ks) {
            bf16x8 afr[6];
            #pragma unroll
            for (int mt = 0; mt < 6; ++mt)
                afr[mt] = *(const bf16x8*)(Al + (mt * 16 + lr) * QS + ks * 32 + lg * 8);
            #pragma unroll
            for (int nt = 0; nt < 4; ++nt) {
                bf16x8 bfr = *(const bf16x8*)(wt + 3 * WMAT +
                                              (w * 64 + nt * 16 + lr) * D_DIM + h * HD + ks * 32 + lg * 8);
                #pragma unroll
                for (int mt = 0; mt < 6; ++mt)
                    Y[mt][nt] = __builtin_amdgcn_mfma_f32_16x16x32_bf16(afr[mt], bfr, Y[mt][nt], 0, 0, 0);
            }
        }
        // no barrier needed here: next QKV phase writes Ql/Kl/Vl which nobody reads now,
        // and the next barrier (after QKV) fences the next Al/Pl writes.
    }

    // ---------------- epilogue: +bo, +x (fp32), LayerNorm, store ----------------
    float bo4[4], gm4[4], bt4[4];
    int cols[4];
    #pragma unroll
    for (int nt = 0; nt < 4; ++nt) {
        cols[nt] = w * 64 + nt * 16 + lr;
        bo4[nt] = bo[cols[nt]]; gm4[nt] = gamma[cols[nt]]; bt4[nt] = beta[cols[nt]];
    }
    #pragma unroll
    for (int mt = 0; mt < 6; ++mt)
        #pragma unroll
        for (int j = 0; j < 4; ++j) {
            int rowl = mt * 16 + lg * 4 + j;
            const float* xrow = x + (row0 + rowl) * (size_t)D_DIM;
            float ps = 0.f, pq = 0.f;
            #pragma unroll
            for (int nt = 0; nt < 4; ++nt) {
                float y = Y[mt][nt][j] + bo4[nt] + xrow[cols[nt]];
                Y[mt][nt][j] = y;
                ps += y; pq += y * y;
            }
            ps += __shfl_xor(ps, 1); pq += __shfl_xor(pq, 1);
            ps += __shfl_xor(ps, 2); pq += __shfl_xor(pq, 2);
            ps += __shfl_xor(ps, 4); pq += __shfl_xor(pq, 4);
            ps += __shfl_xor(ps, 8); pq += __shfl_xor(pq, 8);
            if (lr == 0) { red[rowl * 16 + w * 2] = ps; red[rowl * 16 + w * 2 + 1] = pq; }
        }
    __syncthreads();
    if (tid < ROWS) {
        float s = 0.f, q = 0.f;
        #pragma unroll
        for (int w8 = 0; w8 < 8; ++w8) { s += red[tid * 16 + w8 * 2]; q += red[tid * 16 + w8 * 2 + 1]; }
        float mu = s * (1.f / 512.f);
        float var = q * (1.f / 512.f) - mu * mu;
        musig[tid * 2] = mu;
        musig[tid * 2 + 1] = rsqrtf(var + 1e-5f);
    }
    __syncthreads();
    #pragma unroll
    for (int mt = 0; mt < 6; ++mt)
        #pragma unroll
        for (int j = 0; j < 4; ++j) {
            int rowl = mt * 16 + lg * 4 + j;
            float mu = musig[rowl * 2], rs = musig[rowl * 2 + 1];
            float* orow = out + (row0 + rowl) * (size_t)D_DIM;
            #pragma unroll
            for (int nt = 0; nt < 4; ++nt)
                orow[cols[nt]] = (Y[mt][nt][j] - mu) * rs * gm4[nt] + bt4[nt];
        }
}

extern "C" void kernel_launch(void* const* d_in, const int* in_sizes, int n_in,
                              void* d_out, int out_size, void* d_ws, size_t ws_size,
                              hipStream_t stream) {
    (void)in_sizes; (void)n_in; (void)out_size; (void)ws_size;
    const float* x     = (const float*)d_in[0];
    const float* Wq    = (const float*)d_in[1];
    const float* bq    = (const float*)d_in[2];
    const float* Wk    = (const float*)d_in[3];
    const float* bk    = (const float*)d_in[4];
    const float* Wv    = (const float*)d_in[5];
    const float* bv    = (const float*)d_in[6];
    const float* adj   = (const float*)d_in[7];
    const float* Wo    = (const float*)d_in[8];
    const float* bo    = (const float*)d_in[9];
    const float* gamma = (const float*)d_in[10];
    const float* beta  = (const float*)d_in[11];
    unsigned short* wt = (unsigned short*)d_ws;      // 4 * 512*512 bf16 = 2 MiB

    prep_weights<<<4096, 256, 0, stream>>>(Wq, Wk, Wv, Wo, wt);
    fused_attn<<<16384 / G_B, THREADS, SMEM_BYTES, stream>>>(
        x, wt, bq, bk, bv, adj, bo, gamma, beta, (float*)d_out);
}